// Round 3
// baseline (718.758 us; speedup 1.0000x reference)
//
#include <hip/hip_runtime.h>
#include <hip/hip_bf16.h>

#define HID 64

// ---------------------------------------------------------------------------
// Node kernel: per-node linear projections.
//   esrc[n] = x[n]  @ Wsg + bsg          (scalar)
//   edst[n] = x[n]  @ Wdg + bdg          (scalar)
//   ps4[n]  = x0[n] @ Wsp + bsp          (float4)
//   pd4[n]  = x0[n] @ Wdp                (float4)
// Weights staged in LDS (broadcast reads, conflict-free). One thread per node,
// float4 global loads (16B/lane). ~26 MB traffic -> ~4 us, memory-bound.
// ---------------------------------------------------------------------------
__global__ __launch_bounds__(256) void nbo_node_kernel(
    const float* __restrict__ x, const float* __restrict__ x0,
    const float* __restrict__ Wsg, const float* __restrict__ bsg,
    const float* __restrict__ Wdg, const float* __restrict__ bdg,
    const float* __restrict__ Wsp, const float* __restrict__ bsp,
    const float* __restrict__ Wdp,
    float* __restrict__ esrc, float* __restrict__ edst,
    float4* __restrict__ ps4, float4* __restrict__ pd4, int N)
{
    __shared__ float4 s_wsg[16];   // Wsg as 16 float4
    __shared__ float4 s_wdg[16];   // Wdg
    __shared__ float4 s_wsp[64];   // Wsp row-major: row i -> float4 of 4 outputs
    __shared__ float4 s_wdp[64];   // Wdp

    const int tid = threadIdx.x;
    if (tid < 16) {
        s_wsg[tid] = ((const float4*)Wsg)[tid];
        s_wdg[tid] = ((const float4*)Wdg)[tid];
    }
    if (tid < 64) {
        s_wsp[tid] = ((const float4*)Wsp)[tid];
        s_wdp[tid] = ((const float4*)Wdp)[tid];
    }
    __syncthreads();

    const int n = blockIdx.x * 256 + tid;
    if (n >= N) return;

    const float4* xv  = (const float4*)(x  + (size_t)n * HID);
    const float4* x0v = (const float4*)(x0 + (size_t)n * HID);

    float  asg = 0.f, adg = 0.f;
    float4 asp = make_float4(0.f, 0.f, 0.f, 0.f);
    float4 adp = make_float4(0.f, 0.f, 0.f, 0.f);

#pragma unroll
    for (int j = 0; j < 16; ++j) {
        const float4 a = xv[j];
        const float4 b = x0v[j];
        const float4 g = s_wsg[j];
        const float4 h = s_wdg[j];
        asg += a.x * g.x + a.y * g.y + a.z * g.z + a.w * g.w;
        adg += a.x * h.x + a.y * h.y + a.z * h.z + a.w * h.w;
#pragma unroll
        for (int c = 0; c < 4; ++c) {
            const float bx = (&b.x)[c];
            const float4 sp = s_wsp[4 * j + c];
            const float4 dp = s_wdp[4 * j + c];
            asp.x += bx * sp.x; asp.y += bx * sp.y;
            asp.z += bx * sp.z; asp.w += bx * sp.w;
            adp.x += bx * dp.x; adp.y += bx * dp.y;
            adp.z += bx * dp.z; adp.w += bx * dp.w;
        }
    }

    esrc[n] = asg + bsg[0];
    edst[n] = adg + bdg[0];
    ps4[n] = make_float4(asp.x + bsp[0], asp.y + bsp[1],
                         asp.z + bsp[2], asp.w + bsp[3]);
    pd4[n] = adp;
}

// ---------------------------------------------------------------------------
// E1 — pure streaming dot: dotv[e] = y[e] @ Weg + beg.
// No branches, no gathers, no atomics: the 410 MB y stream runs at pure
// HBM bandwidth with nothing on its critical path. ~416 MB -> ~66 us floor.
// ---------------------------------------------------------------------------
__global__ __launch_bounds__(256) void nbo_dot_kernel(
    const float* __restrict__ y, const float* __restrict__ Weg,
    const float* __restrict__ beg, float* __restrict__ dotv, int E)
{
    __shared__ float4 s_weg[16];
    const int tid = threadIdx.x;
    if (tid < 16) s_weg[tid] = ((const float4*)Weg)[tid];
    __syncthreads();

    const int e = blockIdx.x * 256 + tid;
    if (e >= E) return;

    const float4* yv = (const float4*)(y + (size_t)e * HID);
    float acc = 0.f;
#pragma unroll
    for (int j = 0; j < 16; ++j) {
        const float4 a = yv[j];
        const float4 w = s_weg[j];
        acc += a.x * w.x + a.y * w.y + a.z * w.z + a.w * w.w;
    }
    dotv[e] = acc + beg[0];
}

// ---------------------------------------------------------------------------
// E2 — per-edge gather + pair potential + scatter.
// Coalesced streams only (bl, dotv, src, dst = 25.6 MB); the r > 4.0
// early-out now guards only L2-resident gathers and VALU (cutoff is
// hard-zero past 4.0, so skipped edges contribute exactly 0).
//   m  = esrc[src] + edst[dst] + dotv ;  bo = sigmoid(m)
//   f_rep = exp(a0 - P1*r), P1 = exp(a1)   (folded: 5 expf instead of 7)
//   f_att = exp(a2 - P3*r), P3 = exp(a3)
//   V  = cutoff(r) * (f_rep - bo * f_att)
//   atomicAdd(atomwise[dst], V);  block-reduce V -> atomicAdd(energy, sum/N)
// out[0] = energy, out[1..N] = atomwise_energy (both pre-zeroed).
// ---------------------------------------------------------------------------
__global__ __launch_bounds__(256) void nbo_edge_kernel(
    const float* __restrict__ bl, const float* __restrict__ dotv,
    const int* __restrict__ src, const int* __restrict__ dst,
    const float* __restrict__ esrc, const float* __restrict__ edst,
    const float4* __restrict__ ps4, const float4* __restrict__ pd4,
    float* __restrict__ out, int E, float invN)
{
    const int tid = threadIdx.x;
    const int e = blockIdx.x * 256 + tid;
    float V = 0.f;
    if (e < E) {
        const float r  = bl[e];
        const float dv = dotv[e];
        const int   s  = src[e];
        const int   d  = dst[e];

        if (r <= 4.0f) {   // cutoff == 0 beyond 4.0: edge contributes exactly 0
            const float m  = esrc[s] + edst[d] + dv;
            const float bo = 1.0f / (1.0f + __expf(-m));

            const float4 p1 = ps4[s];
            const float4 p2 = pd4[d];
            // Fold the amplitude exp into the decay exp:
            //   P0*exp(-P1*r) = exp(a0 - P1*r)
            const float P1 = __expf(p1.y + p2.y);
            const float P3 = __expf(p1.w + p2.w);
            const float f_rep = __expf(p1.x + p2.x - P1 * r);
            const float f_att = __expf(p1.z + p2.z - P3 * r);

            // cutoff: D=0.1, R=3.9 ; pi/(2D) = pi/0.2
            const float cut = (r < 3.8f)
                ? 1.0f
                : (0.5f - 0.5f * __sinf(15.707963267948966f * (r - 3.9f)));

            V = cut * (f_rep - bo * f_att);
            atomicAdd(out + 1 + d, V);
        }
    }

    // Block reduction of V for the energy mean (one atomic per block).
#pragma unroll
    for (int off = 32; off > 0; off >>= 1)
        V += __shfl_down(V, off);

    __shared__ float s_wsum[4];
    const int wid  = tid >> 6;
    const int lane = tid & 63;
    if (lane == 0) s_wsum[wid] = V;
    __syncthreads();
    if (tid == 0) {
        const float bsum = s_wsum[0] + s_wsum[1] + s_wsum[2] + s_wsum[3];
        atomicAdd(out, bsum * invN);
    }
}

extern "C" void kernel_launch(void* const* d_in, const int* in_sizes, int n_in,
                              void* d_out, int out_size, void* d_ws, size_t ws_size,
                              hipStream_t stream) {
    const float* x   = (const float*)d_in[0];
    const float* x0  = (const float*)d_in[1];
    const float* y   = (const float*)d_in[2];
    const float* bl  = (const float*)d_in[3];
    const int*   src = (const int*)d_in[4];
    const int*   dst = (const int*)d_in[5];
    const float* Wsg = (const float*)d_in[6];
    const float* bsg = (const float*)d_in[7];
    const float* Wdg = (const float*)d_in[8];
    const float* bdg = (const float*)d_in[9];
    const float* Weg = (const float*)d_in[10];
    const float* beg = (const float*)d_in[11];
    const float* Wsp = (const float*)d_in[12];
    const float* bsp = (const float*)d_in[13];
    const float* Wdp = (const float*)d_in[14];

    const int N = in_sizes[0] / HID;
    const int E = in_sizes[3];

    float* out = (float*)d_out;
    float* ws  = (float*)d_ws;

    // ws layout: esrc[N] | edst[N] | ps4[N] (float4) | pd4[N] (float4) | dotv[E]
    float*  w_esrc = ws;
    float*  w_edst = ws + (size_t)N;
    float4* w_ps4  = (float4*)(ws + 2 * (size_t)N);
    float4* w_pd4  = (float4*)(ws + 2 * (size_t)N + 4 * (size_t)N);
    float*  w_dotv = ws + 10 * (size_t)N;

    // d_out is poisoned 0xAA before every timed launch; we accumulate into it.
    (void)hipMemsetAsync(d_out, 0, (size_t)out_size * sizeof(float), stream);

    nbo_node_kernel<<<(N + 255) / 256, 256, 0, stream>>>(
        x, x0, Wsg, bsg, Wdg, bdg, Wsp, bsp, Wdp,
        w_esrc, w_edst, w_ps4, w_pd4, N);

    nbo_dot_kernel<<<(E + 255) / 256, 256, 0, stream>>>(
        y, Weg, beg, w_dotv, E);

    nbo_edge_kernel<<<(E + 255) / 256, 256, 0, stream>>>(
        bl, w_dotv, src, dst,
        w_esrc, w_edst, w_ps4, w_pd4,
        out, E, 1.0f / (float)N);
}

// Round 4
// 617.323 us; speedup vs baseline: 1.1643x; 1.1643x over previous
//
#include <hip/hip_runtime.h>
#include <hip/hip_bf16.h>

#define HID 64

// ---------------------------------------------------------------------------
// Node kernel: per-node linear projections, packed for single-line gathers.
//   spack[2n]   = x0[n] @ Wsp + bsp   (float4)        src-side pair params
//   spack[2n+1] = { x[n] @ Wsg + bsg, 0, 0, 0 }       src-side gate scalar
//   dpack[2n]   = x0[n] @ Wdp          (float4)        dst-side pair params
//   dpack[2n+1] = { x[n] @ Wdg + bdg, 0, 0, 0 }       dst-side gate scalar
// 32B slot per node per side -> the edge kernel's two reads (float4 @ +0,
// float @ +16) always hit the SAME cache line: 2 random lines/edge, not 4.
// ---------------------------------------------------------------------------
__global__ __launch_bounds__(256) void nbo_node_kernel(
    const float* __restrict__ x, const float* __restrict__ x0,
    const float* __restrict__ Wsg, const float* __restrict__ bsg,
    const float* __restrict__ Wdg, const float* __restrict__ bdg,
    const float* __restrict__ Wsp, const float* __restrict__ bsp,
    const float* __restrict__ Wdp,
    float4* __restrict__ spack, float4* __restrict__ dpack, int N)
{
    __shared__ float4 s_wsg[16];   // Wsg as 16 float4
    __shared__ float4 s_wdg[16];   // Wdg
    __shared__ float4 s_wsp[64];   // Wsp row-major: row i -> float4 of 4 outputs
    __shared__ float4 s_wdp[64];   // Wdp

    const int tid = threadIdx.x;
    if (tid < 16) {
        s_wsg[tid] = ((const float4*)Wsg)[tid];
        s_wdg[tid] = ((const float4*)Wdg)[tid];
    }
    if (tid < 64) {
        s_wsp[tid] = ((const float4*)Wsp)[tid];
        s_wdp[tid] = ((const float4*)Wdp)[tid];
    }
    __syncthreads();

    const int n = blockIdx.x * 256 + tid;
    if (n >= N) return;

    const float4* xv  = (const float4*)(x  + (size_t)n * HID);
    const float4* x0v = (const float4*)(x0 + (size_t)n * HID);

    float  asg = 0.f, adg = 0.f;
    float4 asp = make_float4(0.f, 0.f, 0.f, 0.f);
    float4 adp = make_float4(0.f, 0.f, 0.f, 0.f);

#pragma unroll
    for (int j = 0; j < 16; ++j) {
        const float4 a = xv[j];
        const float4 b = x0v[j];
        const float4 g = s_wsg[j];
        const float4 h = s_wdg[j];
        asg += a.x * g.x + a.y * g.y + a.z * g.z + a.w * g.w;
        adg += a.x * h.x + a.y * h.y + a.z * h.z + a.w * h.w;
#pragma unroll
        for (int c = 0; c < 4; ++c) {
            const float bx = (&b.x)[c];
            const float4 sp = s_wsp[4 * j + c];
            const float4 dp = s_wdp[4 * j + c];
            asp.x += bx * sp.x; asp.y += bx * sp.y;
            asp.z += bx * sp.z; asp.w += bx * sp.w;
            adp.x += bx * dp.x; adp.y += bx * dp.y;
            adp.z += bx * dp.z; adp.w += bx * dp.w;
        }
    }

    spack[2 * n]     = make_float4(asp.x + bsp[0], asp.y + bsp[1],
                                   asp.z + bsp[2], asp.w + bsp[3]);
    spack[2 * n + 1] = make_float4(asg + bsg[0], 0.f, 0.f, 0.f);
    dpack[2 * n]     = adp;
    dpack[2 * n + 1] = make_float4(adg + bdg[0], 0.f, 0.f, 0.f);
}

// ---------------------------------------------------------------------------
// Edge kernel (fused, R0 structure): one thread per edge.
//   - y[e]@Weg stream is UNCONDITIONAL (rides free under gather latency;
//     R2 showed that putting it behind the bl[e] branch serializes it).
//   - gathers + transcendentals + atomic are guarded by r <= 4.0 (cutoff is
//     hard-zero past 4.0 -> skipped edges contribute exactly 0). Exec-masked
//     lanes issue no gather addresses: ~20% less of the bottleneck work.
//   - spack/dpack packing: 2 random lines per edge instead of 4.
//   m  = esrc[s] + edst[d] + y@Weg + beg ;  bo = sigmoid(m)
//   f_rep = exp(a0 - P1*r), P1 = exp(a1)   (folded: 5 expf total)
//   f_att = exp(a2 - P3*r), P3 = exp(a3)
//   V  = cutoff(r) * (f_rep - bo * f_att)
//   atomicAdd(atomwise[d], V);  block-reduce V -> atomicAdd(energy, sum/N)
// out[0] = energy, out[1..N] = atomwise_energy (both pre-zeroed).
// ---------------------------------------------------------------------------
__global__ __launch_bounds__(256) void nbo_edge_kernel(
    const float* __restrict__ y, const float* __restrict__ bl,
    const int* __restrict__ src, const int* __restrict__ dst,
    const float* __restrict__ Weg, const float* __restrict__ beg,
    const float4* __restrict__ spack, const float4* __restrict__ dpack,
    float* __restrict__ out, int E, float invN)
{
    __shared__ float4 s_weg[16];
    const int tid = threadIdx.x;
    if (tid < 16) s_weg[tid] = ((const float4*)Weg)[tid];
    __syncthreads();

    const int e = blockIdx.x * 256 + tid;
    float V = 0.f;
    if (e < E) {
        const float r = bl[e];
        const int   s = src[e];
        const int   d = dst[e];

        // y[e] @ Weg  (16 x float4, streaming, unconditional)
        const float4* yv = (const float4*)(y + (size_t)e * HID);
        float dotv = 0.f;
#pragma unroll
        for (int j = 0; j < 16; ++j) {
            const float4 a = yv[j];
            const float4 w = s_weg[j];
            dotv += a.x * w.x + a.y * w.y + a.z * w.z + a.w * w.w;
        }

        if (r <= 4.0f) {   // cutoff == 0 beyond 4.0: edge contributes exactly 0
            // One 32B slot per side: float4 @ +0 and float @ +16 share a line.
            const float4 p1 = spack[2 * s];
            const float  es = ((const float*)(spack + 2 * s + 1))[0];
            const float4 p2 = dpack[2 * d];
            const float  ed = ((const float*)(dpack + 2 * d + 1))[0];

            const float m  = es + ed + dotv + beg[0];
            const float bo = 1.0f / (1.0f + __expf(-m));

            // Fold amplitude exp into the decay exp: P0*exp(-P1*r)=exp(a0-P1*r)
            const float P1 = __expf(p1.y + p2.y);
            const float P3 = __expf(p1.w + p2.w);
            const float f_rep = __expf(p1.x + p2.x - P1 * r);
            const float f_att = __expf(p1.z + p2.z - P3 * r);

            // cutoff: D=0.1, R=3.9 ; pi/(2D) = pi/0.2
            const float cut = (r < 3.8f)
                ? 1.0f
                : (0.5f - 0.5f * __sinf(15.707963267948966f * (r - 3.9f)));

            V = cut * (f_rep - bo * f_att);
            atomicAdd(out + 1 + d, V);
        }
    }

    // Block reduction of V for the energy mean (one atomic per block).
#pragma unroll
    for (int off = 32; off > 0; off >>= 1)
        V += __shfl_down(V, off);

    __shared__ float s_wsum[4];
    const int wid  = tid >> 6;
    const int lane = tid & 63;
    if (lane == 0) s_wsum[wid] = V;
    __syncthreads();
    if (tid == 0) {
        const float bsum = s_wsum[0] + s_wsum[1] + s_wsum[2] + s_wsum[3];
        atomicAdd(out, bsum * invN);
    }
}

extern "C" void kernel_launch(void* const* d_in, const int* in_sizes, int n_in,
                              void* d_out, int out_size, void* d_ws, size_t ws_size,
                              hipStream_t stream) {
    const float* x   = (const float*)d_in[0];
    const float* x0  = (const float*)d_in[1];
    const float* y   = (const float*)d_in[2];
    const float* bl  = (const float*)d_in[3];
    const int*   src = (const int*)d_in[4];
    const int*   dst = (const int*)d_in[5];
    const float* Wsg = (const float*)d_in[6];
    const float* bsg = (const float*)d_in[7];
    const float* Wdg = (const float*)d_in[8];
    const float* bdg = (const float*)d_in[9];
    const float* Weg = (const float*)d_in[10];
    const float* beg = (const float*)d_in[11];
    const float* Wsp = (const float*)d_in[12];
    const float* bsp = (const float*)d_in[13];
    const float* Wdp = (const float*)d_in[14];

    const int N = in_sizes[0] / HID;
    const int E = in_sizes[3];

    float* out = (float*)d_out;
    float* ws  = (float*)d_ws;

    // ws layout: spack[N] (2 float4/node) | dpack[N] (2 float4/node) = 64B/node
    float4* w_spack = (float4*)ws;
    float4* w_dpack = (float4*)ws + 2 * (size_t)N;

    // d_out is poisoned 0xAA before every timed launch; we accumulate into it.
    (void)hipMemsetAsync(d_out, 0, (size_t)out_size * sizeof(float), stream);

    nbo_node_kernel<<<(N + 255) / 256, 256, 0, stream>>>(
        x, x0, Wsg, bsg, Wdg, bdg, Wsp, bsp, Wdp,
        w_spack, w_dpack, N);

    nbo_edge_kernel<<<(E + 255) / 256, 256, 0, stream>>>(
        y, bl, src, dst, Weg, beg,
        w_spack, w_dpack,
        out, E, 1.0f / (float)N);
}